// Round 3
// baseline (342.921 us; speedup 1.0000x reference)
//
#include <hip/hip_runtime.h>
#include <hip/hip_bf16.h>
#include <stdint.h>

#define B_   4
#define S_   2048
#define DIN  1024
#define EMB  1024
#define H_   16
#define HD_  64
#define TOK  (B_*S_)            // 8192
#define NQKV 3072

using bf16  = __hip_bfloat16;
using f32x4 = __attribute__((ext_vector_type(4))) float;
using s16x8 = __attribute__((ext_vector_type(8))) short;
using bf16x8 = __attribute__((ext_vector_type(8))) __bf16;

__device__ __forceinline__ f32x4 mfma16(s16x8 a, s16x8 b, f32x4 c) {
  return __builtin_amdgcn_mfma_f32_16x16x32_bf16(
      __builtin_bit_cast(bf16x8, a), __builtin_bit_cast(bf16x8, b), c, 0, 0, 0);
}

__device__ __forceinline__ void gload_lds16(const void* g, void* l) {
  __builtin_amdgcn_global_load_lds(
      (const __attribute__((address_space(1))) uint32_t*)g,
      (__attribute__((address_space(3))) uint32_t*)l, 16, 0, 0);
}

union U8 { s16x8 v; bf16 b[8]; };

// ---------------------------------------------------------------- f32 -> bf16
__global__ __launch_bounds__(256) void cvt_bf16(const float* __restrict__ in,
                                                bf16* __restrict__ out, int n) {
  int i = (blockIdx.x * 256 + threadIdx.x) * 8;
  if (i >= n) return;
  float4 a = *(const float4*)(in + i);
  float4 b = *(const float4*)(in + i + 4);
  U8 u;
  u.b[0] = __float2bfloat16(a.x); u.b[1] = __float2bfloat16(a.y);
  u.b[2] = __float2bfloat16(a.z); u.b[3] = __float2bfloat16(a.w);
  u.b[4] = __float2bfloat16(b.x); u.b[5] = __float2bfloat16(b.y);
  u.b[6] = __float2bfloat16(b.z); u.b[7] = __float2bfloat16(b.w);
  *(s16x8*)(out + i) = u.v;
}

// ---------------------------------------------------------------- GEMM (TN)
// C[m,n] = sum_k A[m,k]*Bw[n,k] + bias[n].  BM=BN=128, BK=64, 256 thr (4 waves 2x2).
// LDS tiles [128 rows][64 k] bf16, rows are 128B; XOR swizzle on 16B chunks
// (chunk p ^= row&7), applied by pre-swizzling the GLOBAL source column (LDS
// dest stays linear for global_load_lds, rule #21) and XORing the ds_read addr.
// MODE 0: QKV epilogue -> qkvb (Q,K cols) + vb transposed (V cols), bf16.
// MODE 1: fp32 output + bias.
template<int MODE>
__global__ __launch_bounds__(256) void gemm_bt(
    const bf16* __restrict__ A, const bf16* __restrict__ Bw,
    const float* __restrict__ bias,
    bf16* __restrict__ outQK, bf16* __restrict__ outV,
    float* __restrict__ outF, int N, int K)
{
  const int tid  = threadIdx.x;
  const int lane = tid & 63;
  const int w    = tid >> 6;
  const int wm   = w >> 1, wn = w & 1;
  const int bn0  = blockIdx.x * 128;
  const int bm0  = blockIdx.y * 128;

  __shared__ __align__(16) bf16 As[128 * 64];
  __shared__ __align__(16) bf16 Bs[128 * 64];

  f32x4 acc[4][4];
  const f32x4 zero = {0.f, 0.f, 0.f, 0.f};
  for (int mt = 0; mt < 4; ++mt)
    for (int nt = 0; nt < 4; ++nt) acc[mt][nt] = zero;

  for (int kt = 0; kt < K; kt += 64) {
    for (int i = 0; i < 4; ++i) {
      int c   = i * 256 + tid;            // chunk 0..1023 (16B each)
      int row = c >> 3, p = c & 7;
      int sc  = p ^ (row & 7);            // pre-swizzled source column
      gload_lds16(A + (size_t)(bm0 + row) * K + kt + sc * 8, (char*)As + c * 16);
      gload_lds16(Bw + (size_t)(bn0 + row) * K + kt + sc * 8, (char*)Bs + c * 16);
    }
    __syncthreads();

    s16x8 af[4][2], bfr[4][2];
    for (int mt = 0; mt < 4; ++mt)
      for (int kk = 0; kk < 2; ++kk) {
        int row  = wm * 64 + mt * 16 + (lane & 15);
        int byte = row * 128 + (((kk * 4 + (lane >> 4)) ^ (row & 7)) << 4);
        af[mt][kk] = *(const s16x8*)((const char*)As + byte);
      }
    for (int nt = 0; nt < 4; ++nt)
      for (int kk = 0; kk < 2; ++kk) {
        int row  = wn * 64 + nt * 16 + (lane & 15);
        int byte = row * 128 + (((kk * 4 + (lane >> 4)) ^ (row & 7)) << 4);
        bfr[nt][kk] = *(const s16x8*)((const char*)Bs + byte);
      }
    for (int kk = 0; kk < 2; ++kk)
      for (int mt = 0; mt < 4; ++mt)
        for (int nt = 0; nt < 4; ++nt)
          acc[mt][nt] = mfma16(af[mt][kk], bfr[nt][kk], acc[mt][nt]);
    __syncthreads();
  }

  const int col_l = lane & 15;
  const int rgrp  = lane >> 4;
  for (int mt = 0; mt < 4; ++mt)
    for (int nt = 0; nt < 4; ++nt) {
      int n0  = bn0 + wn * 64 + nt * 16;
      int col = n0 + col_l;
      float bv = bias[col];
      if (MODE == 0) {
        int h = col / 192, rem = col % 192;
        int cc = rem / 64, d = rem % 64;     // cc,h uniform over the 16-col tile
        for (int r = 0; r < 4; ++r) {
          int row = bm0 + wm * 64 + mt * 16 + rgrp * 4 + r;
          bf16 bvv = __float2bfloat16(acc[mt][nt][r] + bv);
          if (cc == 2) {
            int bb = row >> 11, s = row & 2047;
            outV[(((size_t)bb * H_ + h) * HD_ + d) * S_ + s] = bvv;   // V^T layout
          } else {
            outQK[(size_t)row * NQKV + col] = bvv;
          }
        }
      } else {
        for (int r = 0; r < 4; ++r) {
          int row = bm0 + wm * 64 + mt * 16 + rgrp * 4 + r;
          outF[(size_t)row * EMB + col] = acc[mt][nt][r] + bv;
        }
      }
    }
}

// ---------------------------------------------------------------- attention
// One block per (64-row Q tile, b*h). 4 waves; wave w owns q rows w*16..w*16+15.
// Q pre-scaled by 0.125 (exact in bf16). K,V^T staged via global_load_lds with
// pre-swizzled source; P through swizzled LDS (own-wave stripe, no barrier).
__global__ __launch_bounds__(256) void attn(const bf16* __restrict__ qkvb,
                                            const bf16* __restrict__ vb,
                                            bf16* __restrict__ ob)
{
  const int tid = threadIdx.x, lane = tid & 63, w = tid >> 6;
  const int qt = blockIdx.x;           // 0..31
  const int bh = blockIdx.y;           // 0..63
  const int bb = bh >> 4, h = bh & 15;
  const int q0 = qt * 64;
  const size_t tokbase = (size_t)bb * S_;

  __shared__ __align__(16) bf16 Ks[64 * 64];
  __shared__ __align__(16) bf16 Vts[64 * 64];   // V^T [d][k]
  __shared__ __align__(16) bf16 Ps[64 * 64];

  // Q fragments (pre-scaled by 1/sqrt(HD) = 0.125, exact power of two)
  s16x8 qf[2];
  {
    int qrow = q0 + w * 16 + (lane & 15);
    const bf16* qp = qkvb + (tokbase + qrow) * NQKV + h * 192 + (lane >> 4) * 8;
    for (int kk = 0; kk < 2; ++kk) {
      U8 u; u.v = *(const s16x8*)(qp + kk * 32);
      for (int j = 0; j < 8; ++j)
        u.b[j] = __float2bfloat16(__bfloat162float(u.b[j]) * 0.125f);
      qf[kk] = u.v;
    }
  }

  float m0[4], l0[4];
  f32x4 o[4];
  const f32x4 zero = {0.f, 0.f, 0.f, 0.f};
  for (int r = 0; r < 4; ++r) { m0[r] = -1e30f; l0[r] = 0.f; }
  for (int dt = 0; dt < 4; ++dt) o[dt] = zero;

  const bf16* Kbase = qkvb + tokbase * NQKV + h * 192 + 64;
  const bf16* Vbase = vb + (size_t)bh * HD_ * S_;

  for (int t = 0; t < S_ / 64; ++t) {
    int kv0 = t * 64;
    for (int i = 0; i < 2; ++i) {
      int c = i * 256 + tid;
      int row = c >> 3, p = c & 7, sc = p ^ (row & 7);
      gload_lds16(Kbase + (size_t)(kv0 + row) * NQKV + sc * 8, (char*)Ks + c * 16);
      gload_lds16(Vbase + (size_t)row * S_ + kv0 + sc * 8, (char*)Vts + c * 16);
    }
    __syncthreads();

    // S = Q K^T  (scaled)
    f32x4 s4[4];
    for (int kt = 0; kt < 4; ++kt) s4[kt] = zero;
    for (int kt = 0; kt < 4; ++kt)
      for (int kk = 0; kk < 2; ++kk) {
        int row  = kt * 16 + (lane & 15);
        int byte = row * 128 + (((kk * 4 + (lane >> 4)) ^ (row & 7)) << 4);
        s16x8 kf = *(const s16x8*)((const char*)Ks + byte);
        s4[kt] = mfma16(qf[kk], kf, s4[kt]);
      }

    // online softmax (rows = w*16 + (lane>>4)*4 + r; reduce over lane&15)
    float mx[4];
    for (int r = 0; r < 4; ++r)
      mx[r] = fmaxf(fmaxf(s4[0][r], s4[1][r]), fmaxf(s4[2][r], s4[3][r]));
    for (int msk = 1; msk <= 8; msk <<= 1)
      for (int r = 0; r < 4; ++r)
        mx[r] = fmaxf(mx[r], __shfl_xor(mx[r], msk, 64));
    float al[4], rs[4];
    for (int r = 0; r < 4; ++r) {
      float mn = fmaxf(m0[r], mx[r]);
      al[r] = __expf(m0[r] - mn);
      m0[r] = mn;
      rs[r] = 0.f;
    }
    for (int kt = 0; kt < 4; ++kt)
      for (int r = 0; r < 4; ++r) {
        float p = __expf(s4[kt][r] - m0[r]);
        s4[kt][r] = p;
        rs[r] += p;
      }
    for (int msk = 1; msk <= 8; msk <<= 1)
      for (int r = 0; r < 4; ++r)
        rs[r] += __shfl_xor(rs[r], msk, 64);
    for (int r = 0; r < 4; ++r) l0[r] = l0[r] * al[r] + rs[r];
    for (int dt = 0; dt < 4; ++dt)
      for (int r = 0; r < 4; ++r) o[dt][r] *= al[r];

    // P -> LDS (bf16, swizzled); own-wave stripe only, no barrier needed
    for (int kt = 0; kt < 4; ++kt)
      for (int r = 0; r < 4; ++r) {
        int prow = w * 16 + (lane >> 4) * 4 + r;
        int byte = (prow * 128 + (kt * 16 + (lane & 15)) * 2) ^ ((prow & 7) << 4);
        *(bf16*)((char*)Ps + byte) = __float2bfloat16(s4[kt][r]);
      }

    // O += P V
    s16x8 pa[2];
    {
      int prow = w * 16 + (lane & 15);
      for (int kk = 0; kk < 2; ++kk) {
        int byte = (prow * 128 + kk * 64 + (lane >> 4) * 16) ^ ((prow & 7) << 4);
        pa[kk] = *(const s16x8*)((const char*)Ps + byte);
      }
    }
    for (int dt = 0; dt < 4; ++dt)
      for (int kk = 0; kk < 2; ++kk) {
        int drow = dt * 16 + (lane & 15);
        int byte = (drow * 128 + kk * 64 + (lane >> 4) * 16) ^ ((drow & 7) << 4);
        s16x8 vf = *(const s16x8*)((const char*)Vts + byte);
        o[dt] = mfma16(pa[kk], vf, o[dt]);
      }
    __syncthreads();
  }

  for (int dt = 0; dt < 4; ++dt)
    for (int r = 0; r < 4; ++r) {
      int qrow = q0 + w * 16 + (lane >> 4) * 4 + r;
      float v = o[dt][r] / l0[r];
      ob[(tokbase + qrow) * EMB + h * 64 + dt * 16 + (lane & 15)] =
          __float2bfloat16(v);
    }
}

// ---------------------------------------------------------------- launcher
// Workspace map (ob aliases xb — xb is dead after the QKV GEMM, ob is born
// after it; every graph replay rewrites xb from x first, so this is
// deterministic):
//   [0,        16MB) xb  -> later ob
//   [16MB,     22MB) wqkvb
//   [22MB,     24MB) woutb
//   [24MB,     72MB) qkvb
//   [72MB,     88MB) vb          total 88 MB
extern "C" void kernel_launch(void* const* d_in, const int* in_sizes, int n_in,
                              void* d_out, int out_size, void* d_ws, size_t ws_size,
                              hipStream_t stream) {
  const float* x    = (const float*)d_in[0];
  const float* Wqkv = (const float*)d_in[1];
  const float* bqkv = (const float*)d_in[2];
  const float* Wout = (const float*)d_in[3];
  const float* bout = (const float*)d_in[4];
  float* out = (float*)d_out;

  char* ws = (char*)d_ws;
  bf16* xb    = (bf16*)(ws);                       // 16,777,216 B
  bf16* wqkvb = (bf16*)(ws + 16777216);            //  6,291,456 B
  bf16* woutb = (bf16*)(ws + 23068672);            //  2,097,152 B
  bf16* qkvb  = (bf16*)(ws + 25165824);            // 50,331,648 B
  bf16* vb    = (bf16*)(ws + 75497472);            // 16,777,216 B
  bf16* ob    = xb;                                // alias (xb dead after gemm0)

  cvt_bf16<<<(TOK * DIN / 8 + 255) / 256, 256, 0, stream>>>(x, xb, TOK * DIN);
  cvt_bf16<<<(NQKV * DIN / 8 + 255) / 256, 256, 0, stream>>>(Wqkv, wqkvb, NQKV * DIN);
  cvt_bf16<<<(EMB * EMB / 8 + 255) / 256, 256, 0, stream>>>(Wout, woutb, EMB * EMB);

  gemm_bt<0><<<dim3(NQKV / 128, TOK / 128), 256, 0, stream>>>(
      xb, wqkvb, bqkv, qkvb, vb, nullptr, NQKV, DIN);

  attn<<<dim3(S_ / 64, B_ * H_), 256, 0, stream>>>(qkvb, vb, ob);

  gemm_bt<1><<<dim3(EMB / 128, TOK / 128), 256, 0, stream>>>(
      ob, woutb, bout, nullptr, nullptr, out, EMB, EMB);
}

// Round 4
// 233.499 us; speedup vs baseline: 1.4686x; 1.4686x over previous
//
#include <hip/hip_runtime.h>
#include <hip/hip_bf16.h>
#include <stdint.h>

#define B_   4
#define S_   2048
#define DIN  1024
#define EMB  1024
#define H_   16
#define HD_  64
#define TOK  (B_*S_)            // 8192
#define NQKV 3072

using bf16  = __hip_bfloat16;
using f32x4 = __attribute__((ext_vector_type(4))) float;
using f32x16 = __attribute__((ext_vector_type(16))) float;
using s16x8 = __attribute__((ext_vector_type(8))) short;
using bf16x8 = __attribute__((ext_vector_type(8))) __bf16;

__device__ __forceinline__ f32x4 mfma16(s16x8 a, s16x8 b, f32x4 c) {
  return __builtin_amdgcn_mfma_f32_16x16x32_bf16(
      __builtin_bit_cast(bf16x8, a), __builtin_bit_cast(bf16x8, b), c, 0, 0, 0);
}
__device__ __forceinline__ f32x16 mfma32(s16x8 a, s16x8 b, f32x16 c) {
  return __builtin_amdgcn_mfma_f32_32x32x16_bf16(
      __builtin_bit_cast(bf16x8, a), __builtin_bit_cast(bf16x8, b), c, 0, 0, 0);
}

__device__ __forceinline__ void gload_lds16(const void* g, void* l) {
  __builtin_amdgcn_global_load_lds(
      (const __attribute__((address_space(1))) uint32_t*)g,
      (__attribute__((address_space(3))) uint32_t*)l, 16, 0, 0);
}

// pack two f32 -> one u32 of 2 bf16 (lo,hi)
__device__ __forceinline__ uint32_t cvtpk_bf16(float lo, float hi) {
  uint32_t r;
  asm("v_cvt_pk_bf16_f32 %0, %1, %2" : "=v"(r) : "v"(lo), "v"(hi));
  return r;
}
// exchange a's lanes 32-63 with b's lanes 0-31
__device__ __forceinline__ void plswap32(uint32_t &a, uint32_t &b) {
  asm("v_permlane32_swap_b32 %0, %1" : "+v"(a), "+v"(b));
}

union U8 { s16x8 v; bf16 b[8]; };
union PaU { uint32_t w[4]; s16x8 v; };

// ---------------------------------------------------------------- f32 -> bf16
__global__ __launch_bounds__(256) void cvt_bf16(const float* __restrict__ in,
                                                bf16* __restrict__ out, int n) {
  int i = (blockIdx.x * 256 + threadIdx.x) * 8;
  if (i >= n) return;
  float4 a = *(const float4*)(in + i);
  float4 b = *(const float4*)(in + i + 4);
  U8 u;
  u.b[0] = __float2bfloat16(a.x); u.b[1] = __float2bfloat16(a.y);
  u.b[2] = __float2bfloat16(a.z); u.b[3] = __float2bfloat16(a.w);
  u.b[4] = __float2bfloat16(b.x); u.b[5] = __float2bfloat16(b.y);
  u.b[6] = __float2bfloat16(b.z); u.b[7] = __float2bfloat16(b.w);
  *(s16x8*)(out + i) = u.v;
}

// ---------------------------------------------------------------- GEMM (TN)
// (unchanged from round 3 — passed; ~100 µs combined, address next round)
template<int MODE>
__global__ __launch_bounds__(256) void gemm_bt(
    const bf16* __restrict__ A, const bf16* __restrict__ Bw,
    const float* __restrict__ bias,
    bf16* __restrict__ outQK, bf16* __restrict__ outV,
    float* __restrict__ outF, int N, int K)
{
  const int tid  = threadIdx.x;
  const int lane = tid & 63;
  const int w    = tid >> 6;
  const int wm   = w >> 1, wn = w & 1;
  const int bn0  = blockIdx.x * 128;
  const int bm0  = blockIdx.y * 128;

  __shared__ __align__(16) bf16 As[128 * 64];
  __shared__ __align__(16) bf16 Bs[128 * 64];

  f32x4 acc[4][4];
  const f32x4 zero = {0.f, 0.f, 0.f, 0.f};
  for (int mt = 0; mt < 4; ++mt)
    for (int nt = 0; nt < 4; ++nt) acc[mt][nt] = zero;

  for (int kt = 0; kt < K; kt += 64) {
    for (int i = 0; i < 4; ++i) {
      int c   = i * 256 + tid;
      int row = c >> 3, p = c & 7;
      int sc  = p ^ (row & 7);
      gload_lds16(A + (size_t)(bm0 + row) * K + kt + sc * 8, (char*)As + c * 16);
      gload_lds16(Bw + (size_t)(bn0 + row) * K + kt + sc * 8, (char*)Bs + c * 16);
    }
    __syncthreads();

    s16x8 af[4][2], bfr[4][2];
    for (int mt = 0; mt < 4; ++mt)
      for (int kk = 0; kk < 2; ++kk) {
        int row  = wm * 64 + mt * 16 + (lane & 15);
        int byte = row * 128 + (((kk * 4 + (lane >> 4)) ^ (row & 7)) << 4);
        af[mt][kk] = *(const s16x8*)((const char*)As + byte);
      }
    for (int nt = 0; nt < 4; ++nt)
      for (int kk = 0; kk < 2; ++kk) {
        int row  = wn * 64 + nt * 16 + (lane & 15);
        int byte = row * 128 + (((kk * 4 + (lane >> 4)) ^ (row & 7)) << 4);
        bfr[nt][kk] = *(const s16x8*)((const char*)Bs + byte);
      }
    for (int kk = 0; kk < 2; ++kk)
      for (int mt = 0; mt < 4; ++mt)
        for (int nt = 0; nt < 4; ++nt)
          acc[mt][nt] = mfma16(af[mt][kk], bfr[nt][kk], acc[mt][nt]);
    __syncthreads();
  }

  const int col_l = lane & 15;
  const int rgrp  = lane >> 4;
  for (int mt = 0; mt < 4; ++mt)
    for (int nt = 0; nt < 4; ++nt) {
      int n0  = bn0 + wn * 64 + nt * 16;
      int col = n0 + col_l;
      float bv = bias[col];
      if (MODE == 0) {
        int h = col / 192, rem = col % 192;
        int cc = rem / 64, d = rem % 64;
        for (int r = 0; r < 4; ++r) {
          int row = bm0 + wm * 64 + mt * 16 + rgrp * 4 + r;
          bf16 bvv = __float2bfloat16(acc[mt][nt][r] + bv);
          if (cc == 2) {
            int bb = row >> 11, s = row & 2047;
            outV[(((size_t)bb * H_ + h) * HD_ + d) * S_ + s] = bvv;   // V^T
          } else {
            outQK[(size_t)row * NQKV + col] = bvv;
          }
        }
      } else {
        for (int r = 0; r < 4; ++r) {
          int row = bm0 + wm * 64 + mt * 16 + rgrp * 4 + r;
          outF[(size_t)row * EMB + col] = acc[mt][nt][r] + bv;
        }
      }
    }
}

// ---------------------------------------------------------------- attention v2
// Swapped-operand 32x32x16 flash attention, softmax fully in registers.
// Block = 4 waves x 32 q-rows = 128 q-rows; KVBLK=64; K/V^T double-buffered LDS.
// QK^T computed as mfma(K, Q) so lane owns q-row (lane&31): P[kv] in 2x f32x16,
// kv = (r&3)+8*(r>>2)+4*(lane>>5) (+32 for second half).  Row-reduce = in-lane
// tree + one shfl_xor(32).  P->bf16 A-frags via cvt_pk + permlane32_swap (T12).
// Defer-max (T13), THR=11 in log2 domain (Q pre-scaled by 0.125*log2e, exp2).
// XCD-affinity block swizzle (T1, bijective): all 16 q-tiles of a (b,h) on one
// XCD -> K/V working set 4 MB/XCD (= L2 size).
__global__ __launch_bounds__(256) void attn2(const bf16* __restrict__ qkvb,
                                             const bf16* __restrict__ vb,
                                             bf16* __restrict__ ob)
{
  const int tid = threadIdx.x, lane = tid & 63, w = tid >> 6;
  const int hi = lane >> 5, l31 = lane & 31;
  const int f  = blockIdx.x;                 // 0..1023
  const int bh = (f & 7) | ((f >> 7) << 3);  // XCD = f&7 keeps bh on one XCD
  const int qt = (f >> 3) & 15;
  const int bb = bh >> 4, h = bh & 15;
  const int q0 = qt * 128;
  const size_t tokbase = (size_t)bb * S_;

  __shared__ __align__(16) bf16 Ks[2][64 * 64];
  __shared__ __align__(16) bf16 Vts[2][64 * 64];   // V^T [d][kv]

  // Q fragments (B-operand: col=l31=q, k=16*ks+8*hi+e), scaled 0.125*log2e
  s16x8 qf[4];
  {
    const int qrow = q0 + w * 32 + l31;
    const bf16* qp = qkvb + (tokbase + qrow) * NQKV + h * 192 + hi * 8;
    #pragma unroll
    for (int ks = 0; ks < 4; ++ks) {
      U8 u; u.v = *(const s16x8*)(qp + ks * 16);
      #pragma unroll
      for (int j = 0; j < 8; ++j)
        u.b[j] = __float2bfloat16(__bfloat162float(u.b[j]) * 0.18033688011112042f);
      qf[ks] = u.v;
    }
  }

  f32x16 zero16;
  #pragma unroll
  for (int i = 0; i < 16; ++i) zero16[i] = 0.f;
  f32x16 oA = zero16, oB = zero16;   // d = l31 and 32+l31; q = pattern(r,hi)
  float m = -__builtin_inff(), l0 = 0.f;

  const bf16* Kbase = qkvb + tokbase * NQKV + h * 192 + 64;
  const bf16* Vbase = vb + (size_t)bh * HD_ * S_;

  auto STAGE = [&](int b, int t) {
    const int kv0 = t * 64;
    #pragma unroll
    for (int i = 0; i < 2; ++i) {
      int c = i * 256 + tid;
      int row = c >> 3, p = c & 7, sc = p ^ (row & 7);
      gload_lds16(Kbase + (size_t)(kv0 + row) * NQKV + sc * 8,
                  (char*)Ks[b] + c * 16);
      gload_lds16(Vbase + (size_t)row * S_ + kv0 + sc * 8,
                  (char*)Vts[b] + c * 16);
    }
  };

  STAGE(0, 0);
  __syncthreads();

  int cur = 0;
  for (int t = 0; t < S_ / 64; ++t) {
    if (t < S_ / 64 - 1) STAGE(cur ^ 1, t + 1);   // issue-early (T14 spirit)

    // ---- S^T = K · Q^T   (lane: q=l31; kv in-register)
    f32x16 pA = zero16, pB = zero16;
    #pragma unroll
    for (int ks = 0; ks < 4; ++ks) {
      {
        int arow = l31;
        int byte = arow * 128 + (((2 * ks + hi) ^ (arow & 7)) << 4);
        s16x8 kf = *(const s16x8*)((const char*)Ks[cur] + byte);
        pA = mfma32(kf, qf[ks], pA);
      }
      {
        int arow = 32 + l31;
        int byte = arow * 128 + (((2 * ks + hi) ^ (arow & 7)) << 4);
        s16x8 kf = *(const s16x8*)((const char*)Ks[cur] + byte);
        pB = mfma32(kf, qf[ks], pB);
      }
    }

    // ---- row max: in-lane tree over 32 + partner combine
    float mx8[8];
    #pragma unroll
    for (int i = 0; i < 8; ++i)
      mx8[i] = fmaxf(fmaxf(pA[i], pA[i + 8]), fmaxf(pB[i], pB[i + 8]));
    float mx4a = fmaxf(mx8[0], mx8[4]), mx4b = fmaxf(mx8[1], mx8[5]);
    float mx4c = fmaxf(mx8[2], mx8[6]), mx4d = fmaxf(mx8[3], mx8[7]);
    float pmax = fmaxf(fmaxf(mx4a, mx4b), fmaxf(mx4c, mx4d));
    pmax = fmaxf(pmax, __shfl_xor(pmax, 32));

    // ---- defer-max rescale (rare after t=0); THR=11 log2-units
    if (__any(pmax > m + 11.0f)) {
      float mn = fmaxf(m, pmax);
      float al = __builtin_amdgcn_exp2f(m - mn);   // exp2(-inf)=0 handles t=0
      m = mn;
      l0 *= al;
      #pragma unroll
      for (int r = 0; r < 16; ++r) {
        float alr = __shfl(al, (r & 3) + 8 * (r >> 2) + 4 * hi);
        oA[r] *= alr; oB[r] *= alr;
      }
    }

    // ---- exp2 + partial row-sum (partner holds other 32 kv)
    #pragma unroll
    for (int r = 0; r < 16; ++r) {
      pA[r] = __builtin_amdgcn_exp2f(pA[r] - m);
      pB[r] = __builtin_amdgcn_exp2f(pB[r] - m);
    }
    float s8[8];
    #pragma unroll
    for (int i = 0; i < 8; ++i)
      s8[i] = (pA[i] + pA[i + 8]) + (pB[i] + pB[i + 8]);
    l0 += ((s8[0] + s8[1]) + (s8[2] + s8[3])) +
          ((s8[4] + s8[5]) + (s8[6] + s8[7]));

    // ---- pack P (cvt_pk + permlane32_swap) and PV per 16-kv step
    #pragma unroll
    for (int s = 0; s < 4; ++s) {
      const int sub = s & 1;
      const f32x16 &ph = (s < 2) ? pA : pB;
      uint32_t L0 = cvtpk_bf16(ph[8 * sub + 0], ph[8 * sub + 1]);
      uint32_t L1 = cvtpk_bf16(ph[8 * sub + 2], ph[8 * sub + 3]);
      uint32_t H0 = cvtpk_bf16(ph[8 * sub + 4], ph[8 * sub + 5]);
      uint32_t H1 = cvtpk_bf16(ph[8 * sub + 6], ph[8 * sub + 7]);
      plswap32(L0, H0);   // L0: lo lanes keep own, hi lanes get partner's H0
      plswap32(L1, H1);
      PaU pa; pa.w[0] = L0; pa.w[1] = L1; pa.w[2] = H0; pa.w[3] = H1;
      {
        int vrow = l31;
        int byte = vrow * 128 + (((2 * s + hi) ^ (vrow & 7)) << 4);
        s16x8 vf = *(const s16x8*)((const char*)Vts[cur] + byte);
        oA = mfma32(pa.v, vf, oA);
      }
      {
        int vrow = 32 + l31;
        int byte = vrow * 128 + (((2 * s + hi) ^ (vrow & 7)) << 4);
        s16x8 vf = *(const s16x8*)((const char*)Vts[cur] + byte);
        oB = mfma32(pa.v, vf, oB);
      }
    }
    __syncthreads();   // implicit vmcnt(0): next buffer staged & current drained
    cur ^= 1;
  }

  // ---- epilogue: combine partner l0, normalize, write
  float l0t = l0 + __shfl_xor(l0, 32);
  float inv = 1.0f / l0t;                  // lane's q = l31
  #pragma unroll
  for (int r = 0; r < 16; ++r) {
    int q = (r & 3) + 8 * (r >> 2) + 4 * hi;
    float invr = __shfl(inv, q);           // lanes q / q+32 both hold row q's inv
    int qrow = q0 + w * 32 + q;
    bf16* op = ob + (tokbase + qrow) * EMB + h * 64 + l31;
    op[0]  = __float2bfloat16(oA[r] * invr);
    op[32] = __float2bfloat16(oB[r] * invr);
  }
}

// ---------------------------------------------------------------- launcher
// Workspace map (ob aliases xb — xb dead after gemm0, rewritten every replay):
//   [0,16MB) xb->ob  [16,22) wqkvb  [22,24) woutb  [24,72) qkvb  [72,88) vb
extern "C" void kernel_launch(void* const* d_in, const int* in_sizes, int n_in,
                              void* d_out, int out_size, void* d_ws, size_t ws_size,
                              hipStream_t stream) {
  const float* x    = (const float*)d_in[0];
  const float* Wqkv = (const float*)d_in[1];
  const float* bqkv = (const float*)d_in[2];
  const float* Wout = (const float*)d_in[3];
  const float* bout = (const float*)d_in[4];
  float* out = (float*)d_out;

  char* ws = (char*)d_ws;
  bf16* xb    = (bf16*)(ws);
  bf16* wqkvb = (bf16*)(ws + 16777216);
  bf16* woutb = (bf16*)(ws + 23068672);
  bf16* qkvb  = (bf16*)(ws + 25165824);
  bf16* vb    = (bf16*)(ws + 75497472);
  bf16* ob    = xb;

  cvt_bf16<<<(TOK * DIN / 8 + 255) / 256, 256, 0, stream>>>(x, xb, TOK * DIN);
  cvt_bf16<<<(NQKV * DIN / 8 + 255) / 256, 256, 0, stream>>>(Wqkv, wqkvb, NQKV * DIN);
  cvt_bf16<<<(EMB * EMB / 8 + 255) / 256, 256, 0, stream>>>(Wout, woutb, EMB * EMB);

  gemm_bt<0><<<dim3(NQKV / 128, TOK / 128), 256, 0, stream>>>(
      xb, wqkvb, bqkv, qkvb, vb, nullptr, NQKV, DIN);

  attn2<<<dim3(16 * 64), 256, 0, stream>>>(qkvb, vb, ob);

  gemm_bt<1><<<dim3(EMB / 128, TOK / 128), 256, 0, stream>>>(
      ob, woutb, bout, nullptr, nullptr, out, EMB, EMB);
}

// Round 5
// 222.168 us; speedup vs baseline: 1.5435x; 1.0510x over previous
//
#include <hip/hip_runtime.h>
#include <hip/hip_bf16.h>
#include <stdint.h>

#define B_   4
#define S_   2048
#define DIN  1024
#define EMB  1024
#define H_   16
#define HD_  64
#define TOK  (B_*S_)            // 8192
#define NQKV 3072

using bf16  = __hip_bfloat16;
using f32x4 = __attribute__((ext_vector_type(4))) float;
using f32x16 = __attribute__((ext_vector_type(16))) float;
using s16x8 = __attribute__((ext_vector_type(8))) short;
using bf16x8 = __attribute__((ext_vector_type(8))) __bf16;

__device__ __forceinline__ f32x4 mfma16(s16x8 a, s16x8 b, f32x4 c) {
  return __builtin_amdgcn_mfma_f32_16x16x32_bf16(
      __builtin_bit_cast(bf16x8, a), __builtin_bit_cast(bf16x8, b), c, 0, 0, 0);
}
__device__ __forceinline__ f32x16 mfma32(s16x8 a, s16x8 b, f32x16 c) {
  return __builtin_amdgcn_mfma_f32_32x32x16_bf16(
      __builtin_bit_cast(bf16x8, a), __builtin_bit_cast(bf16x8, b), c, 0, 0, 0);
}

__device__ __forceinline__ void gload_lds16(const void* g, void* l) {
  __builtin_amdgcn_global_load_lds(
      (const __attribute__((address_space(1))) uint32_t*)g,
      (__attribute__((address_space(3))) uint32_t*)l, 16, 0, 0);
}

// pack two f32 -> one u32 of 2 bf16 (lo,hi)
__device__ __forceinline__ uint32_t cvtpk_bf16(float lo, float hi) {
  uint32_t r;
  asm("v_cvt_pk_bf16_f32 %0, %1, %2" : "=v"(r) : "v"(lo), "v"(hi));
  return r;
}
// exchange a's lanes 32-63 with b's lanes 0-31
__device__ __forceinline__ void plswap32(uint32_t &a, uint32_t &b) {
  asm("v_permlane32_swap_b32 %0, %1" : "+v"(a), "+v"(b));
}

union U8 { s16x8 v; bf16 b[8]; };
union PaU { uint32_t w[4]; s16x8 v; };

// ---------------------------------------------------------------- f32 -> bf16
__global__ __launch_bounds__(256) void cvt_bf16(const float* __restrict__ in,
                                                bf16* __restrict__ out, int n) {
  int i = (blockIdx.x * 256 + threadIdx.x) * 8;
  if (i >= n) return;
  float4 a = *(const float4*)(in + i);
  float4 b = *(const float4*)(in + i + 4);
  U8 u;
  u.b[0] = __float2bfloat16(a.x); u.b[1] = __float2bfloat16(a.y);
  u.b[2] = __float2bfloat16(a.z); u.b[3] = __float2bfloat16(a.w);
  u.b[4] = __float2bfloat16(b.x); u.b[5] = __float2bfloat16(b.y);
  u.b[6] = __float2bfloat16(b.z); u.b[7] = __float2bfloat16(b.w);
  *(s16x8*)(out + i) = u.v;
}

// ---------------------------------------------------------------- GEMM (TN)
// (unchanged from round 3/4 — passed)
template<int MODE>
__global__ __launch_bounds__(256) void gemm_bt(
    const bf16* __restrict__ A, const bf16* __restrict__ Bw,
    const float* __restrict__ bias,
    bf16* __restrict__ outQK, bf16* __restrict__ outV,
    float* __restrict__ outF, int N, int K)
{
  const int tid  = threadIdx.x;
  const int lane = tid & 63;
  const int w    = tid >> 6;
  const int wm   = w >> 1, wn = w & 1;
  const int bn0  = blockIdx.x * 128;
  const int bm0  = blockIdx.y * 128;

  __shared__ __align__(16) bf16 As[128 * 64];
  __shared__ __align__(16) bf16 Bs[128 * 64];

  f32x4 acc[4][4];
  const f32x4 zero = {0.f, 0.f, 0.f, 0.f};
  for (int mt = 0; mt < 4; ++mt)
    for (int nt = 0; nt < 4; ++nt) acc[mt][nt] = zero;

  for (int kt = 0; kt < K; kt += 64) {
    for (int i = 0; i < 4; ++i) {
      int c   = i * 256 + tid;
      int row = c >> 3, p = c & 7;
      int sc  = p ^ (row & 7);
      gload_lds16(A + (size_t)(bm0 + row) * K + kt + sc * 8, (char*)As + c * 16);
      gload_lds16(Bw + (size_t)(bn0 + row) * K + kt + sc * 8, (char*)Bs + c * 16);
    }
    __syncthreads();

    s16x8 af[4][2], bfr[4][2];
    for (int mt = 0; mt < 4; ++mt)
      for (int kk = 0; kk < 2; ++kk) {
        int row  = wm * 64 + mt * 16 + (lane & 15);
        int byte = row * 128 + (((kk * 4 + (lane >> 4)) ^ (row & 7)) << 4);
        af[mt][kk] = *(const s16x8*)((const char*)As + byte);
      }
    for (int nt = 0; nt < 4; ++nt)
      for (int kk = 0; kk < 2; ++kk) {
        int row  = wn * 64 + nt * 16 + (lane & 15);
        int byte = row * 128 + (((kk * 4 + (lane >> 4)) ^ (row & 7)) << 4);
        bfr[nt][kk] = *(const s16x8*)((const char*)Bs + byte);
      }
    for (int kk = 0; kk < 2; ++kk)
      for (int mt = 0; mt < 4; ++mt)
        for (int nt = 0; nt < 4; ++nt)
          acc[mt][nt] = mfma16(af[mt][kk], bfr[nt][kk], acc[mt][nt]);
    __syncthreads();
  }

  const int col_l = lane & 15;
  const int rgrp  = lane >> 4;
  for (int mt = 0; mt < 4; ++mt)
    for (int nt = 0; nt < 4; ++nt) {
      int n0  = bn0 + wn * 64 + nt * 16;
      int col = n0 + col_l;
      float bv = bias[col];
      if (MODE == 0) {
        int h = col / 192, rem = col % 192;
        int cc = rem / 64, d = rem % 64;
        for (int r = 0; r < 4; ++r) {
          int row = bm0 + wm * 64 + mt * 16 + rgrp * 4 + r;
          bf16 bvv = __float2bfloat16(acc[mt][nt][r] + bv);
          if (cc == 2) {
            int bb = row >> 11, s = row & 2047;
            outV[(((size_t)bb * H_ + h) * HD_ + d) * S_ + s] = bvv;   // V^T
          } else {
            outQK[(size_t)row * NQKV + col] = bvv;
          }
        }
      } else {
        for (int r = 0; r < 4; ++r) {
          int row = bm0 + wm * 64 + mt * 16 + rgrp * 4 + r;
          outF[(size_t)row * EMB + col] = acc[mt][nt][r] + bv;
        }
      }
    }
}

// ---------------------------------------------------------------- attention v3
// Swapped-operand 32x32x16 flash attention, softmax in registers.
// Round-5 changes vs v2 (sync structure identical):
//  * QBLK=256: 8 waves x 32 q-rows, grid 512 (2 blocks/CU) — halves per-wave
//    staging work and K/V refetch.
//  * -m folded into the QK MFMA accumulator init (nm16 = lane-broadcast -m):
//    QK produces S-m directly; deletes 32 v_sub + 32 acc-zero-inits per iter.
//    m init = 0 (not -inf) so no inf-inf NaN; defer-max THR=11 (log2 domain,
//    Q pre-scaled by 0.125*log2e) caps exp2 args; rescale branch (rare) does
//    pA-=pmax, nm16-=pmax, l0*=exp2(-pmax), oA/oB*=per-row factor.
__global__ __launch_bounds__(512) void attn2(const bf16* __restrict__ qkvb,
                                             const bf16* __restrict__ vb,
                                             bf16* __restrict__ ob)
{
  const int tid = threadIdx.x, lane = tid & 63, w = tid >> 6;  // w 0..7
  const int hi = lane >> 5, l31 = lane & 31;
  const int f  = blockIdx.x;                       // 0..511
  const int bh = (f & 7) | (((f >> 6) & 7) << 3);  // XCD = f&7 pins bh to one XCD
  const int qt = (f >> 3) & 7;
  const int bb = bh >> 4, h = bh & 15;
  const int q0 = qt * 256;
  const size_t tokbase = (size_t)bb * S_;

  __shared__ __align__(16) bf16 Ks[2][64 * 64];
  __shared__ __align__(16) bf16 Vts[2][64 * 64];   // V^T [d][kv]

  // Q fragments (B-operand: col=l31=q, k=16*ks+8*hi+e), scaled 0.125*log2e
  s16x8 qf[4];
  {
    const int qrow = q0 + w * 32 + l31;
    const bf16* qp = qkvb + (tokbase + qrow) * NQKV + h * 192 + hi * 8;
    #pragma unroll
    for (int ks = 0; ks < 4; ++ks) {
      U8 u; u.v = *(const s16x8*)(qp + ks * 16);
      #pragma unroll
      for (int j = 0; j < 8; ++j)
        u.b[j] = __float2bfloat16(__bfloat162float(u.b[j]) * 0.18033688011112042f);
      qf[ks] = u.v;
    }
  }

  f32x16 zero16;
  #pragma unroll
  for (int i = 0; i < 16; ++i) zero16[i] = 0.f;
  f32x16 oA = zero16, oB = zero16;   // C-layout: col=d(=l31/+32), row=q pattern
  f32x16 nm16 = zero16;              // all elems = -m (m starts at 0)
  float l0 = 0.f;

  const bf16* Kbase = qkvb + tokbase * NQKV + h * 192 + 64;
  const bf16* Vbase = vb + (size_t)bh * HD_ * S_;

  auto STAGE = [&](int b, int t) {
    const int kv0 = t * 64;
    const int c = tid;                       // 512 thr = 512 chunks per array
    const int row = c >> 3, p = c & 7, sc = p ^ (row & 7);
    gload_lds16(Kbase + (size_t)(kv0 + row) * NQKV + sc * 8,
                (char*)Ks[b] + c * 16);
    gload_lds16(Vbase + (size_t)row * S_ + kv0 + sc * 8,
                (char*)Vts[b] + c * 16);
  };

  STAGE(0, 0);
  __syncthreads();

  int cur = 0;
  for (int t = 0; t < S_ / 64; ++t) {
    if (t < S_ / 64 - 1) STAGE(cur ^ 1, t + 1);   // issue-early

    // ---- S^T - m = K · Q^T + (-m)   (lane: q=l31; kv in-register)
    f32x16 pA, pB;
    #pragma unroll
    for (int ks = 0; ks < 4; ++ks) {
      {
        int arow = l31;
        int byte = arow * 128 + (((2 * ks + hi) ^ (arow & 7)) << 4);
        s16x8 kf = *(const s16x8*)((const char*)Ks[cur] + byte);
        pA = mfma32(kf, qf[ks], ks == 0 ? nm16 : pA);
      }
      {
        int arow = 32 + l31;
        int byte = arow * 128 + (((2 * ks + hi) ^ (arow & 7)) << 4);
        s16x8 kf = *(const s16x8*)((const char*)Ks[cur] + byte);
        pB = mfma32(kf, qf[ks], ks == 0 ? nm16 : pB);
      }
    }

    // ---- row max of (S-m): in-lane tree + partner combine
    float mx8[8];
    #pragma unroll
    for (int i = 0; i < 8; ++i)
      mx8[i] = fmaxf(fmaxf(pA[i], pA[i + 8]), fmaxf(pB[i], pB[i + 8]));
    float pmax = fmaxf(fmaxf(fmaxf(mx8[0], mx8[4]), fmaxf(mx8[1], mx8[5])),
                       fmaxf(fmaxf(mx8[2], mx8[6]), fmaxf(mx8[3], mx8[7])));
    pmax = fmaxf(pmax, __shfl_xor(pmax, 32));

    // ---- defer-max rescale (rare); everything already in S-m domain
    if (__any(pmax > 11.0f)) {
      float al = __builtin_amdgcn_exp2f(-pmax);
      l0 *= al;
      #pragma unroll
      for (int r = 0; r < 16; ++r) {
        float alr = __shfl(al, (r & 3) + 8 * (r >> 2) + 4 * hi);
        oA[r] *= alr; oB[r] *= alr;
      }
      #pragma unroll
      for (int r = 0; r < 16; ++r) { pA[r] -= pmax; pB[r] -= pmax; }
      #pragma unroll
      for (int i = 0; i < 16; ++i) nm16[i] -= pmax;
    }

    // ---- exp2 (args <= 11 guaranteed) + partial row-sum
    #pragma unroll
    for (int r = 0; r < 16; ++r) {
      pA[r] = __builtin_amdgcn_exp2f(pA[r]);
      pB[r] = __builtin_amdgcn_exp2f(pB[r]);
    }
    float s8[8];
    #pragma unroll
    for (int i = 0; i < 8; ++i)
      s8[i] = (pA[i] + pA[i + 8]) + (pB[i] + pB[i + 8]);
    l0 += ((s8[0] + s8[1]) + (s8[2] + s8[3])) +
          ((s8[4] + s8[5]) + (s8[6] + s8[7]));

    // ---- pack P (cvt_pk + permlane32_swap) and PV per 16-kv step
    #pragma unroll
    for (int s = 0; s < 4; ++s) {
      const int sub = s & 1;
      const f32x16 &ph = (s < 2) ? pA : pB;
      uint32_t L0 = cvtpk_bf16(ph[8 * sub + 0], ph[8 * sub + 1]);
      uint32_t L1 = cvtpk_bf16(ph[8 * sub + 2], ph[8 * sub + 3]);
      uint32_t H0 = cvtpk_bf16(ph[8 * sub + 4], ph[8 * sub + 5]);
      uint32_t H1 = cvtpk_bf16(ph[8 * sub + 6], ph[8 * sub + 7]);
      plswap32(L0, H0);
      plswap32(L1, H1);
      PaU pa; pa.w[0] = L0; pa.w[1] = L1; pa.w[2] = H0; pa.w[3] = H1;
      {
        int vrow = l31;
        int byte = vrow * 128 + (((2 * s + hi) ^ (vrow & 7)) << 4);
        s16x8 vf = *(const s16x8*)((const char*)Vts[cur] + byte);
        oA = mfma32(pa.v, vf, oA);
      }
      {
        int vrow = 32 + l31;
        int byte = vrow * 128 + (((2 * s + hi) ^ (vrow & 7)) << 4);
        s16x8 vf = *(const s16x8*)((const char*)Vts[cur] + byte);
        oB = mfma32(pa.v, vf, oB);
      }
    }
    __syncthreads();   // one vmcnt(0)+barrier per tile
    cur ^= 1;
  }

  // ---- epilogue: combine partner l0, normalize, write
  float l0t = l0 + __shfl_xor(l0, 32);
  float inv = 1.0f / l0t;                  // lane's q = l31
  #pragma unroll
  for (int r = 0; r < 16; ++r) {
    int q = (r & 3) + 8 * (r >> 2) + 4 * hi;
    float invr = __shfl(inv, q);
    int qrow = q0 + w * 32 + q;
    bf16* op = ob + (tokbase + qrow) * EMB + h * 64 + l31;
    op[0]  = __float2bfloat16(oA[r] * invr);
    op[32] = __float2bfloat16(oB[r] * invr);
  }
}

// ---------------------------------------------------------------- launcher
// Workspace map (ob aliases xb — xb dead after gemm0, rewritten every replay):
//   [0,16MB) xb->ob  [16,22) wqkvb  [22,24) woutb  [24,72) qkvb  [72,88) vb
extern "C" void kernel_launch(void* const* d_in, const int* in_sizes, int n_in,
                              void* d_out, int out_size, void* d_ws, size_t ws_size,
                              hipStream_t stream) {
  const float* x    = (const float*)d_in[0];
  const float* Wqkv = (const float*)d_in[1];
  const float* bqkv = (const float*)d_in[2];
  const float* Wout = (const float*)d_in[3];
  const float* bout = (const float*)d_in[4];
  float* out = (float*)d_out;

  char* ws = (char*)d_ws;
  bf16* xb    = (bf16*)(ws);
  bf16* wqkvb = (bf16*)(ws + 16777216);
  bf16* woutb = (bf16*)(ws + 23068672);
  bf16* qkvb  = (bf16*)(ws + 25165824);
  bf16* vb    = (bf16*)(ws + 75497472);
  bf16* ob    = xb;

  cvt_bf16<<<(TOK * DIN / 8 + 255) / 256, 256, 0, stream>>>(x, xb, TOK * DIN);
  cvt_bf16<<<(NQKV * DIN / 8 + 255) / 256, 256, 0, stream>>>(Wqkv, wqkvb, NQKV * DIN);
  cvt_bf16<<<(EMB * EMB / 8 + 255) / 256, 256, 0, stream>>>(Wout, woutb, EMB * EMB);

  gemm_bt<0><<<dim3(NQKV / 128, TOK / 128), 256, 0, stream>>>(
      xb, wqkvb, bqkv, qkvb, vb, nullptr, NQKV, DIN);

  attn2<<<dim3(512), 512, 0, stream>>>(qkvb, vb, ob);

  gemm_bt<1><<<dim3(EMB / 128, TOK / 128), 256, 0, stream>>>(
      ob, woutb, bout, nullptr, nullptr, out, EMB, EMB);
}